// Round 1
// baseline (594.387 us; speedup 1.0000x reference)
//
#include <hip/hip_runtime.h>

// PointPillarScatter: out[b, c, z*NY*NX + y*NX + x] = pillar_features[p, c]
// Inverted to a gather: winner[b][s] = max p writing slot s (last-wins),
// then one fully-coalesced streaming pass over the 439 MB output.

#define NXx 432
#define NYy 496
#define SS  (NXx * NYy)   // 214272, divisible by 4
#define CC  64

__global__ void winner_kernel(const int* __restrict__ cb,
                              const int* __restrict__ cz,
                              const int* __restrict__ cy,
                              const int* __restrict__ cx,
                              int* __restrict__ winner, int P) {
    int p = blockIdx.x * blockDim.x + threadIdx.x;
    if (p < P) {
        int idx = cz[p] + cy[p] * NXx + cx[p];
        int slot = cb[p] * SS + idx;
        atomicMax(&winner[slot], p);   // device-scope by default; last (max p) wins
    }
}

__global__ void gather_kernel(const float* __restrict__ pf,
                              const int* __restrict__ winner,
                              float* __restrict__ out, int total4) {
    int stride = gridDim.x * blockDim.x;
    for (int i = blockIdx.x * blockDim.x + threadIdx.x; i < total4; i += stride) {
        int flat = i << 2;                 // flat fp32 index into out, < 2^27
        int plane = flat / SS;             // b*CC + c  (magic-mul, const divisor)
        int s     = flat - plane * SS;     // spatial offset, multiple of 4
        int c     = plane & (CC - 1);
        int b     = plane >> 6;
        const int4 w = *reinterpret_cast<const int4*>(&winner[b * SS + s]);
        float4 o;
        o.x = (w.x >= 0) ? pf[w.x * CC + c] : 0.0f;
        o.y = (w.y >= 0) ? pf[w.y * CC + c] : 0.0f;
        o.z = (w.z >= 0) ? pf[w.z * CC + c] : 0.0f;
        o.w = (w.w >= 0) ? pf[w.w * CC + c] : 0.0f;
        *reinterpret_cast<float4*>(&out[flat]) = o;
    }
}

extern "C" void kernel_launch(void* const* d_in, const int* in_sizes, int n_in,
                              void* d_out, int out_size, void* d_ws, size_t ws_size,
                              hipStream_t stream) {
    const float* pf = (const float*)d_in[0];
    const int* cb   = (const int*)d_in[1];
    const int* cz   = (const int*)d_in[2];
    const int* cy   = (const int*)d_in[3];
    const int* cx   = (const int*)d_in[4];
    float* out      = (float*)d_out;

    const int P = in_sizes[1];                 // number of pillars
    const int B = out_size / (CC * SS);        // batch size (8)

    int* winner = (int*)d_ws;                  // B*SS ints = 6.86 MB
    hipMemsetAsync(winner, 0xFF, (size_t)B * SS * sizeof(int), stream);  // -1 fill

    winner_kernel<<<(P + 255) / 256, 256, 0, stream>>>(cb, cz, cy, cx, winner, P);

    const int total4 = out_size >> 2;          // 27,426,816 float4s
    int blocks = (total4 + 255) / 256;
    if (blocks > 2048) blocks = 2048;          // grid-stride, ~8 blocks/CU
    gather_kernel<<<blocks, 256, 0, stream>>>(pf, winner, out, total4);
}